// Round 5
// baseline (564.220 us; speedup 1.0000x reference)
//
#include <hip/hip_runtime.h>

#define NN     200000
#define MPAD   200064   // 1563 * 128
#define NGRAPH 1024

typedef __bf16 bf16x8 __attribute__((ext_vector_type(8)));
typedef float  f32x4  __attribute__((ext_vector_type(4)));
typedef float  f32x2  __attribute__((ext_vector_type(2)));
typedef unsigned short u16x8 __attribute__((ext_vector_type(8)));

// ---------- helpers ----------
__device__ __forceinline__ unsigned short f2bu(float f) {
    unsigned u = __float_as_uint(f);
    unsigned r = (u + 0x7FFFu + ((u >> 16) & 1u)) >> 16;
    return (unsigned short)r;
}
__device__ __forceinline__ float b2f(unsigned short u) {
    return __uint_as_float(((unsigned)u) << 16);
}
__device__ __forceinline__ void async16(const void* g, void* l) {
    __builtin_amdgcn_global_load_lds(
        (const __attribute__((address_space(1))) void*)g,
        (__attribute__((address_space(3))) void*)l, 16, 0, 0);
}

// ---------- kernel 1: wcatT[n][k] = [Wg1|Wn1][k][n] as bf16 ----------
__global__ __launch_bounds__(256) void convert_w(
    const float* __restrict__ Wg1, const float* __restrict__ Wn1,
    unsigned short* __restrict__ wcatT) {
    int i = blockIdx.x * 256 + threadIdx.x;       // grid 512 -> exactly 512*256
    int n = i >> 8, k = i & 255;
    float v = (n < 256) ? Wg1[k * 256 + n] : Wn1[k * 256 + (n - 256)];
    wcatT[i] = f2bu(v);
}

// ---------- kernel 2: fused  h_n = relu(x@Wn1+b), alpha = relu(x@Wg1)@Wg2 --
// Block: 128 rows x all K=256 x all N=512. A staged once (fp32->bf16, XOR
// swizzle, ds_write). B (L2-hot) staged per (ct,kc) via global_load_lds.
// Wave tiling 4x1: wave owns rows wave*32..+31 for the full 128-col tile.
// ct 0,1 (gate cols): alpha computed in-register, never written to HBM.
// ct 2,3 (node cols): h_n written bf16 [MPAD,256].
__global__ __launch_bounds__(256) void gemm_fused(
    const float* __restrict__ x,              // [NN,256] fp32
    const unsigned short* __restrict__ Bt,    // [512,256] bf16
    const float* __restrict__ bn1,            // [256]
    const float* __restrict__ Wg2,            // [256,8] fp32
    unsigned short* __restrict__ hn,          // [MPAD,256] bf16
    float* __restrict__ alpha) {              // [NN,8] fp32
    __shared__ unsigned short As[128 * 256];  // 64 KB
    __shared__ unsigned short Bs[128 * 32];   // 8 KB
    __shared__ float alpha_s[128 * 8];        // 4 KB  (total 76 KB -> 2 blk/CU)
    const int t    = threadIdx.x;
    const int lane = t & 63;
    const int wave = t >> 6;
    const int quad = lane >> 4;
    const int frow = lane & 15;
    const size_t m0 = (size_t)blockIdx.x * 128;

    for (int i = t; i < 1024; i += 256) alpha_s[i] = 0.0f;

    // ---- stage A panel: thread t -> row t>>1, chunks (t&1)*16 + w
    {
        const int r = t >> 1;
        const int cbase = (t & 1) * 16;
        const bool valid = (m0 + r) < NN;
        const float* xr = x + (m0 + r) * 256;
        #pragma unroll
        for (int w = 0; w < 16; ++w) {
            const int c = cbase + w;
            float4 a = {0.f, 0.f, 0.f, 0.f}, b = {0.f, 0.f, 0.f, 0.f};
            if (valid) {
                a = *(const float4*)(xr + c * 8);
                b = *(const float4*)(xr + c * 8 + 4);
            }
            u16x8 p;
            p[0] = f2bu(a.x); p[1] = f2bu(a.y); p[2] = f2bu(a.z); p[3] = f2bu(a.w);
            p[4] = f2bu(b.x); p[5] = f2bu(b.y); p[6] = f2bu(b.z); p[7] = f2bu(b.w);
            *(u16x8*)&As[r * 256 + ((c ^ (r & 7)) * 8)] = p;
        }
    }

    f32x4 acc[2][8];
    const int brow0 = wave * 32 + (lane >> 2);
    const int bch   = lane & 3;

    #pragma unroll 1
    for (int ct = 0; ct < 4; ++ct) {
        const int n0 = ct * 128;
        #pragma unroll
        for (int i = 0; i < 2; ++i)
            #pragma unroll
            for (int j = 0; j < 8; ++j) acc[i][j] = (f32x4){0.f, 0.f, 0.f, 0.f};

        #pragma unroll 1
        for (int kc = 0; kc < 8; ++kc) {
            #pragma unroll
            for (int it = 0; it < 2; ++it) {
                const int br = brow0 + it * 16;
                async16(Bt + (size_t)(n0 + br) * 256 + kc * 32 + ((bch ^ (br & 3)) * 8),
                        Bs + wave * 1024 + it * 512);
            }
            __syncthreads();       // drains A ds_writes (first iter) + B vmcnt
            const int ska = (kc * 4 + quad) ^ (frow & 7);
            const int skb = quad ^ (frow & 3);
            bf16x8 af0 = *(const bf16x8*)&As[(wave * 32 + frow) * 256 + ska * 8];
            bf16x8 af1 = *(const bf16x8*)&As[(wave * 32 + 16 + frow) * 256 + ska * 8];
            #pragma unroll
            for (int j = 0; j < 8; ++j) {
                bf16x8 bf = *(const bf16x8*)&Bs[(j * 16 + frow) * 32 + skb * 8];
                acc[0][j] = __builtin_amdgcn_mfma_f32_16x16x32_bf16(af0, bf, acc[0][j], 0, 0, 0);
                acc[1][j] = __builtin_amdgcn_mfma_f32_16x16x32_bf16(af1, bf, acc[1][j], 0, 0, 0);
            }
            __syncthreads();       // protect Bs before restage
        }

        if (ct < 2) {
            // alpha contribution: per lane 8 rows (i,r); fold across frow lanes
            const bool b0 = frow & 1, b1 = frow & 2, b2 = frow & 4;
            const int brev = ((frow & 1) << 2) | (frow & 2) | ((frow >> 2) & 1);
            #pragma unroll
            for (int i = 0; i < 2; ++i) {
                float s[4][8];
                #pragma unroll
                for (int r = 0; r < 4; ++r)
                    #pragma unroll
                    for (int h = 0; h < 8; ++h) s[r][h] = 0.f;
                #pragma unroll
                for (int j = 0; j < 8; ++j) {
                    const float* wrow = Wg2 + (size_t)(n0 + j * 16 + frow) * 8;
                    float4 w0 = *(const float4*)wrow;
                    float4 w1 = *(const float4*)(wrow + 4);
                    #pragma unroll
                    for (int r = 0; r < 4; ++r) {
                        float hv = fmaxf(acc[i][j][r], 0.f);   // gate has no bias
                        s[r][0] += hv * w0.x; s[r][1] += hv * w0.y;
                        s[r][2] += hv * w0.z; s[r][3] += hv * w0.w;
                        s[r][4] += hv * w1.x; s[r][5] += hv * w1.y;
                        s[r][6] += hv * w1.z; s[r][7] += hv * w1.w;
                    }
                }
                #pragma unroll
                for (int r = 0; r < 4; ++r) {
                    float t0, t1, t2, t3, u0, u1, w;
                    {   // fold xor-1: keep low heads on b0=0 lanes
                        float s0 = b0 ? s[r][0] : s[r][4]; t0 = (b0 ? s[r][4] : s[r][0]) + __shfl_xor(s0, 1);
                        float s1 = b0 ? s[r][1] : s[r][5]; t1 = (b0 ? s[r][5] : s[r][1]) + __shfl_xor(s1, 1);
                        float s2 = b0 ? s[r][2] : s[r][6]; t2 = (b0 ? s[r][6] : s[r][2]) + __shfl_xor(s2, 1);
                        float s3 = b0 ? s[r][3] : s[r][7]; t3 = (b0 ? s[r][7] : s[r][3]) + __shfl_xor(s3, 1);
                    }
                    {   // fold xor-2
                        float s0 = b1 ? t0 : t2; u0 = (b1 ? t2 : t0) + __shfl_xor(s0, 2);
                        float s1 = b1 ? t1 : t3; u1 = (b1 ? t3 : t1) + __shfl_xor(s1, 2);
                    }
                    {   // fold xor-4
                        float s0 = b2 ? u0 : u1; w = (b2 ? u1 : u0) + __shfl_xor(s0, 4);
                    }
                    const float tot = w + __shfl_xor(w, 8);
                    if (frow < 8) {
                        const int row_local = wave * 32 + i * 16 + quad * 4 + r;
                        alpha_s[row_local * 8 + brev] += tot;   // unique (row,head) per lane
                    }
                }
            }
        } else {
            #pragma unroll
            for (int i = 0; i < 2; ++i)
                #pragma unroll
                for (int j = 0; j < 8; ++j) {
                    const int col = n0 - 256 + j * 16 + frow;
                    const float bv = bn1[col];
                    #pragma unroll
                    for (int r = 0; r < 4; ++r) {
                        size_t row = m0 + wave * 32 + i * 16 + quad * 4 + r;
                        hn[row * 256 + col] = f2bu(fmaxf(acc[i][j][r] + bv, 0.f));
                    }
                }
        }
    }
    __syncthreads();
    {   // alpha writeout: rows m0..m0+127 are contiguous [row*8+h]
        const size_t row = m0 + (t >> 1);
        if (row < NN)
            *(float4*)&alpha[row * 8 + (t & 1) * 4] = *(const float4*)&alpha_s[t * 4];
    }
}

// ---------- kernel 3: softmax + gated segment-sum + tiny GEMV ----------
__device__ __forceinline__ int lower_bound(const int* __restrict__ b, int key) {
    int lo = 0, hi = NN;
    while (lo < hi) { int mid = (lo + hi) >> 1; if (b[mid] < key) lo = mid + 1; else hi = mid; }
    return lo;
}

__global__ __launch_bounds__(256) void pool2(
    const float* __restrict__ alpha, const unsigned short* __restrict__ hn,
    const float* __restrict__ Wn2, const float* __restrict__ bn2,
    const int* __restrict__ batch, float* __restrict__ out) {
    __shared__ float red[256];
    __shared__ float mh[8], ih[8];
    __shared__ float gate_s[32][8];
    __shared__ float Gs[256 * 8];
    const int g = blockIdx.x, t = threadIdx.x;
    const int start = lower_bound(batch, g);
    const int end   = lower_bound(batch, g + 1);
    const int hd = t & 7;

    float mloc = -INFINITY;
    for (int n = start + (t >> 3); n < end; n += 32)
        mloc = fmaxf(mloc, alpha[n * 8 + hd]);
    red[t] = mloc; __syncthreads();
    for (int off = 128; off >= 8; off >>= 1) {
        if (t < off) red[t] = fmaxf(red[t], red[t + off]);
        __syncthreads();
    }
    if (t < 8) mh[t] = red[t];
    __syncthreads();
    const float mm = mh[hd];

    float sloc = 0.f;
    for (int n = start + (t >> 3); n < end; n += 32)
        sloc += __expf(alpha[n * 8 + hd] - mm);
    red[t] = sloc; __syncthreads();
    for (int off = 128; off >= 8; off >>= 1) {
        if (t < off) red[t] += red[t + off];
        __syncthreads();
    }
    if (t < 8) ih[t] = 1.0f / (red[t] + 1e-16f);
    __syncthreads();

    f32x2 G2[4] = {};
    for (int c0 = start; c0 < end; c0 += 32) {
        const int cn = min(32, end - c0);
        __syncthreads();
        if (t < cn * 8)
            gate_s[t >> 3][t & 7] =
                __expf(alpha[(c0 + (t >> 3)) * 8 + (t & 7)] - mh[t & 7]) * ih[t & 7];
        __syncthreads();
        for (int j = 0; j < cn; ++j) {
            float hv = b2f(hn[(size_t)(c0 + j) * 256 + t]);
            f32x2 h2 = {hv, hv};
            const f32x2* gp = (const f32x2*)&gate_s[j][0];
            G2[0] += gp[0] * h2; G2[1] += gp[1] * h2;
            G2[2] += gp[2] * h2; G2[3] += gp[3] * h2;
        }
    }
    __syncthreads();
    #pragma unroll
    for (int i = 0; i < 4; ++i) *(f32x2*)&Gs[t * 8 + i * 2] = G2[i];
    __syncthreads();

    float acc = 0.f;
    #pragma unroll 4
    for (int k = 0; k < 256; ++k)
        acc += Gs[k * 8 + hd] * Wn2[k * 256 + t];
    const float sg = (end > start) ? 1.0f : 0.0f;
    out[g * 256 + t] = acc + sg * bn2[t];
}

// ---------- launch ----------
extern "C" void kernel_launch(void* const* d_in, const int* in_sizes, int n_in,
                              void* d_out, int out_size, void* d_ws, size_t ws_size,
                              hipStream_t stream) {
    const float* x     = (const float*)d_in[0];
    const int*   batch = (const int*)d_in[1];
    const float* Wg1   = (const float*)d_in[2];
    const float* Wg2   = (const float*)d_in[3];
    const float* Wn1   = (const float*)d_in[4];
    const float* bn1   = (const float*)d_in[5];
    const float* Wn2   = (const float*)d_in[6];
    const float* bn2   = (const float*)d_in[7];
    float* out = (float*)d_out;

    unsigned short* hn    = (unsigned short*)d_ws;            // MPAD*256 bf16
    unsigned short* wcatT = hn + (size_t)MPAD * 256;          // 512*256 bf16
    float* alpha = (float*)(wcatT + 512 * 256);               // NN*8 fp32

    convert_w<<<512, 256, 0, stream>>>(Wg1, Wn1, wcatT);
    gemm_fused<<<1563, 256, 0, stream>>>(x, wcatT, bn1, Wg2, hn, alpha);
    pool2<<<NGRAPH, 256, 0, stream>>>(alpha, hn, Wn2, bn2, batch, out);
}

// Round 6
// 535.351 us; speedup vs baseline: 1.0539x; 1.0539x over previous
//
#include <hip/hip_runtime.h>

#define NN     200000
#define MPAD   200064   // 1563 * 128
#define NGRAPH 1024

typedef __bf16 bf16x8 __attribute__((ext_vector_type(8)));
typedef float  f32x4  __attribute__((ext_vector_type(4)));
typedef float  f32x2  __attribute__((ext_vector_type(2)));
typedef unsigned short u16x8 __attribute__((ext_vector_type(8)));

// ---------- helpers ----------
__device__ __forceinline__ unsigned short f2bu(float f) {
    unsigned u = __float_as_uint(f);
    unsigned r = (u + 0x7FFFu + ((u >> 16) & 1u)) >> 16;
    return (unsigned short)r;
}
__device__ __forceinline__ float b2f(unsigned short u) {
    return __uint_as_float(((unsigned)u) << 16);
}
__device__ __forceinline__ void async16(const void* g, void* l) {
    __builtin_amdgcn_global_load_lds(
        (const __attribute__((address_space(1))) void*)g,
        (__attribute__((address_space(3))) void*)l, 16, 0, 0);
}

// ---------- kernel 1: weight prep ----------
// wcatT[n][k] = [Wg1|Wn1][k][n] bf16;  wg2T[16][256]: rows 0-7 = bf16 hi of
// Wg2 col h, rows 8-15 = bf16 residual (hi+lo MFMA = fp32-accurate Wg2).
__global__ __launch_bounds__(256) void convert_w(
    const float* __restrict__ Wg1, const float* __restrict__ Wn1,
    const float* __restrict__ Wg2,
    unsigned short* __restrict__ wcatT, unsigned short* __restrict__ wg2T) {
    int i = blockIdx.x * 256 + threadIdx.x;
    if (i < 512 * 256) {
        int n = i >> 8, k = i & 255;
        float v = (n < 256) ? Wg1[k * 256 + n] : Wn1[k * 256 + (n - 256)];
        wcatT[i] = f2bu(v);
    } else if (i < 512 * 256 + 4096) {
        int j = i - 512 * 256;
        int hh = j >> 8, k = j & 255;            // hh 0..15
        float w = Wg2[k * 8 + (hh & 7)];
        unsigned short hi = f2bu(w);
        wg2T[j] = (hh < 8) ? hi : f2bu(w - b2f(hi));
    }
}

// ---------- kernel 2: fused cast + GEMM ----------
// hg = relu(x@Wg1), hn = relu(x@Wn1 + bn1).  Block: 128 rows x K=256 x N=512.
// A staged once: fp32 x loaded coalesced (half-wave = one row's 16 chunks),
// converted in-register, ds_write_b128 into XOR-swizzled panel.
// B tiles (16 KB, L2-hot) staged per (ct,kc) via global_load_lds.
__global__ __launch_bounds__(256) void gemm_fx(
    const float* __restrict__ x,              // [NN,256] fp32
    const unsigned short* __restrict__ Bt,    // [512,256] bf16
    const float* __restrict__ bn1,            // [256]
    unsigned short* __restrict__ hg,          // [MPAD,256] bf16
    unsigned short* __restrict__ hn) {        // [MPAD,256] bf16
    __shared__ unsigned short As[128 * 256];  // 64 KB
    __shared__ unsigned short Bs[128 * 64];   // 16 KB
    const int t    = threadIdx.x;
    const int lane = t & 63;
    const int wave = t >> 6;
    const int wm = wave >> 1, wn = wave & 1;
    const int quad = lane >> 4;
    const int frow = lane & 15;
    const size_t m0 = (size_t)blockIdx.x * 128;

    // ---- stage A: wave w covers rows w*32..+31; half-wave = one row/instr
    {
        const int chalf = lane & 31;          // 16-B chunk 0..31
        const int roff  = lane >> 5;          // 0/1
        #pragma unroll 4
        for (int it = 0; it < 16; ++it) {
            const int r = wave * 32 + it * 2 + roff;
            const size_t grow = m0 + r;
            float4 a = {0.f, 0.f, 0.f, 0.f}, b = {0.f, 0.f, 0.f, 0.f};
            if (grow < NN) {
                const float* xr = x + grow * 256 + chalf * 8;
                a = *(const float4*)xr;
                b = *(const float4*)(xr + 4);
            }
            u16x8 p;
            p[0] = f2bu(a.x); p[1] = f2bu(a.y); p[2] = f2bu(a.z); p[3] = f2bu(a.w);
            p[4] = f2bu(b.x); p[5] = f2bu(b.y); p[6] = f2bu(b.z); p[7] = f2bu(b.w);
            *(u16x8*)&As[r * 256 + ((chalf ^ (r & 7)) * 8)] = p;
        }
    }

    // B staging pattern
    const int schunk = lane & 7;
    const int srow0  = wave * 32 + (lane >> 3);
    const int swb    = (schunk ^ (srow0 & 7)) * 8;
    unsigned short* lB = Bs + wave * 2048;

    f32x4 acc[4][4];
    #pragma unroll 1
    for (int ct = 0; ct < 4; ++ct) {
        const int n0 = ct * 128;
        #pragma unroll
        for (int i = 0; i < 4; ++i)
            #pragma unroll
            for (int j = 0; j < 4; ++j) acc[i][j] = (f32x4){0.f, 0.f, 0.f, 0.f};

        #pragma unroll 1
        for (int kc = 0; kc < 4; ++kc) {
            #pragma unroll
            for (int is = 0; is < 4; ++is)
                async16(Bt + (size_t)(n0 + srow0 + is * 8) * 256 + kc * 64 + swb,
                        lB + is * 512);
            __syncthreads();     // drains A ds_writes (first pass) + B vmcnt
            #pragma unroll
            for (int kk = 0; kk < 2; ++kk) {
                const int sa = (kc * 8 + kk * 4 + quad) ^ (frow & 7);
                const int sb = (kk * 4 + quad) ^ (frow & 7);
                bf16x8 af[4], bf[4];
                #pragma unroll
                for (int i = 0; i < 4; ++i)
                    af[i] = *(const bf16x8*)&As[(wm * 64 + i * 16 + frow) * 256 + sa * 8];
                #pragma unroll
                for (int j = 0; j < 4; ++j)
                    bf[j] = *(const bf16x8*)&Bs[(wn * 64 + j * 16 + frow) * 64 + sb * 8];
                #pragma unroll
                for (int i = 0; i < 4; ++i)
                    #pragma unroll
                    for (int j = 0; j < 4; ++j)
                        acc[i][j] = __builtin_amdgcn_mfma_f32_16x16x32_bf16(
                            af[i], bf[j], acc[i][j], 0, 0, 0);
            }
            __syncthreads();     // protect Bs before restage
        }

        const int rbase = wm * 64 + (quad << 2);
        if (ct < 2) {            // gate half: no bias, relu, -> hg
            #pragma unroll
            for (int i = 0; i < 4; ++i)
                #pragma unroll
                for (int r = 0; r < 4; ++r) {
                    size_t row = m0 + rbase + i * 16 + r;
                    #pragma unroll
                    for (int j = 0; j < 4; ++j) {
                        const int col = n0 + wn * 64 + j * 16 + frow;
                        hg[row * 256 + col] = f2bu(fmaxf(acc[i][j][r], 0.f));
                    }
                }
        } else {                 // node half: +bn1, relu, -> hn
            float bv[4];
            #pragma unroll
            for (int j = 0; j < 4; ++j)
                bv[j] = bn1[n0 - 256 + wn * 64 + j * 16 + frow];
            #pragma unroll
            for (int i = 0; i < 4; ++i)
                #pragma unroll
                for (int r = 0; r < 4; ++r) {
                    size_t row = m0 + rbase + i * 16 + r;
                    #pragma unroll
                    for (int j = 0; j < 4; ++j) {
                        const int col = n0 - 256 + wn * 64 + j * 16 + frow;
                        hn[row * 256 + col] = f2bu(fmaxf(acc[i][j][r] + bv[j], 0.f));
                    }
                }
        }
    }
}

// ---------- kernel 3: alpha = hg @ Wg2 via MFMA (hi+lo split) ----------
__global__ __launch_bounds__(256) void alpha_mfma(
    const unsigned short* __restrict__ hg,    // [MPAD,256] bf16
    const unsigned short* __restrict__ wg2T,  // [16,256] bf16
    float* __restrict__ alpha) {              // [NN,8]
    __shared__ unsigned short As[128 * 256];  // 64 KB
    const int t    = threadIdx.x;
    const int lane = t & 63;
    const int wave = t >> 6;
    const int frow = lane & 15;
    const int quad = lane >> 4;
    const size_t m0 = (size_t)blockIdx.x * 128;

    {
        const int roff = lane >> 5;
        const int s    = lane & 31;
        #pragma unroll
        for (int it = 0; it < 16; ++it) {
            int r = wave * 32 + it * 2 + roff;
            async16(hg + (m0 + r) * 256 + ((s ^ (r & 7)) * 8),
                    As + (wave * 32 + it * 2) * 256);
        }
    }
    bf16x8 bw[8];
    #pragma unroll
    for (int kk = 0; kk < 8; ++kk)
        bw[kk] = *(const bf16x8*)(wg2T + frow * 256 + kk * 32 + quad * 8);
    __syncthreads();

    f32x4 acc[2] = {};
    #pragma unroll
    for (int kk = 0; kk < 8; ++kk) {
        const int sa = (kk * 4 + quad) ^ (frow & 7);
        #pragma unroll
        for (int mt = 0; mt < 2; ++mt) {
            bf16x8 af = *(const bf16x8*)(As + (wave * 32 + mt * 16 + frow) * 256 + sa * 8);
            acc[mt] = __builtin_amdgcn_mfma_f32_16x16x32_bf16(af, bw[kk], acc[mt], 0, 0, 0);
        }
    }
    #pragma unroll
    for (int mt = 0; mt < 2; ++mt)
        #pragma unroll
        for (int r = 0; r < 4; ++r) {
            float v = acc[mt][r];
            v += __shfl_xor(v, 8);            // hi (col h) + lo (col h+8)
            size_t row = m0 + wave * 32 + mt * 16 + quad * 4 + r;
            if (frow < 8 && row < NN) alpha[row * 8 + frow] = v;
        }
}

// ---------- kernel 4: softmax + gated segment-sum + tiny GEMV ----------
__device__ __forceinline__ int lower_bound(const int* __restrict__ b, int key) {
    int lo = 0, hi = NN;
    while (lo < hi) { int mid = (lo + hi) >> 1; if (b[mid] < key) lo = mid + 1; else hi = mid; }
    return lo;
}

__global__ __launch_bounds__(256) void pool2(
    const float* __restrict__ alpha, const unsigned short* __restrict__ hn,
    const float* __restrict__ Wn2, const float* __restrict__ bn2,
    const int* __restrict__ batch, float* __restrict__ out) {
    __shared__ float red[256];
    __shared__ float mh[8], ih[8];
    __shared__ float gate_s[32][8];
    __shared__ float Gs[256 * 8];
    const int g = blockIdx.x, t = threadIdx.x;
    const int start = lower_bound(batch, g);
    const int end   = lower_bound(batch, g + 1);
    const int hd = t & 7;

    float mloc = -INFINITY;
    for (int n = start + (t >> 3); n < end; n += 32)
        mloc = fmaxf(mloc, alpha[n * 8 + hd]);
    red[t] = mloc; __syncthreads();
    for (int off = 128; off >= 8; off >>= 1) {
        if (t < off) red[t] = fmaxf(red[t], red[t + off]);
        __syncthreads();
    }
    if (t < 8) mh[t] = red[t];
    __syncthreads();
    const float mm = mh[hd];

    float sloc = 0.f;
    for (int n = start + (t >> 3); n < end; n += 32)
        sloc += __expf(alpha[n * 8 + hd] - mm);
    red[t] = sloc; __syncthreads();
    for (int off = 128; off >= 8; off >>= 1) {
        if (t < off) red[t] += red[t + off];
        __syncthreads();
    }
    if (t < 8) ih[t] = 1.0f / (red[t] + 1e-16f);
    __syncthreads();

    f32x2 G2[4] = {};
    for (int c0 = start; c0 < end; c0 += 32) {
        const int cn = min(32, end - c0);
        __syncthreads();
        if (t < cn * 8)
            gate_s[t >> 3][t & 7] =
                __expf(alpha[(c0 + (t >> 3)) * 8 + (t & 7)] - mh[t & 7]) * ih[t & 7];
        __syncthreads();
        for (int j = 0; j < cn; ++j) {
            float hv = b2f(hn[(size_t)(c0 + j) * 256 + t]);
            f32x2 h2 = {hv, hv};
            const f32x2* gp = (const f32x2*)&gate_s[j][0];
            G2[0] += gp[0] * h2; G2[1] += gp[1] * h2;
            G2[2] += gp[2] * h2; G2[3] += gp[3] * h2;
        }
    }
    __syncthreads();
    #pragma unroll
    for (int i = 0; i < 4; ++i) *(f32x2*)&Gs[t * 8 + i * 2] = G2[i];
    __syncthreads();

    float acc = 0.f;
    #pragma unroll 4
    for (int k = 0; k < 256; ++k)
        acc += Gs[k * 8 + hd] * Wn2[k * 256 + t];
    const float sg = (end > start) ? 1.0f : 0.0f;
    out[g * 256 + t] = acc + sg * bn2[t];
}

// ---------- launch ----------
extern "C" void kernel_launch(void* const* d_in, const int* in_sizes, int n_in,
                              void* d_out, int out_size, void* d_ws, size_t ws_size,
                              hipStream_t stream) {
    const float* x     = (const float*)d_in[0];
    const int*   batch = (const int*)d_in[1];
    const float* Wg1   = (const float*)d_in[2];
    const float* Wg2   = (const float*)d_in[3];
    const float* Wn1   = (const float*)d_in[4];
    const float* bn1   = (const float*)d_in[5];
    const float* Wn2   = (const float*)d_in[6];
    const float* bn2   = (const float*)d_in[7];
    float* out = (float*)d_out;

    unsigned short* hg    = (unsigned short*)d_ws;            // MPAD*256 bf16
    unsigned short* hn    = hg + (size_t)MPAD * 256;          // MPAD*256 bf16
    unsigned short* wcatT = hn + (size_t)MPAD * 256;          // 512*256 bf16
    unsigned short* wg2T  = wcatT + 512 * 256;                // 16*256 bf16
    float* alpha = (float*)(wg2T + 16 * 256);                 // NN*8 fp32

    convert_w<<<528, 256, 0, stream>>>(Wg1, Wn1, Wg2, wcatT, wg2T);
    gemm_fx<<<1563, 256, 0, stream>>>(x, wcatT, bn1, hg, hn);
    alpha_mfma<<<1563, 256, 0, stream>>>(hg, wg2T, alpha);
    pool2<<<NGRAPH, 256, 0, stream>>>(alpha, hn, Wn2, bn2, batch, out);
}